// Round 1
// baseline (239.794 us; speedup 1.0000x reference)
//
#include <hip/hip_runtime.h>
#include <hip/hip_bf16.h>
#include <stdint.h>

// Problem constants
#define TSEQ   2048
#define DMODEL 1024
#define NHEAD  16
#define HDIM   64
#define MROWS  4096   // B*T

typedef __attribute__((ext_vector_type(8))) __bf16 bf16x8;
typedef __attribute__((ext_vector_type(4))) float f32x4;
typedef __attribute__((ext_vector_type(8))) unsigned short u16x8;

__device__ __forceinline__ unsigned short f2bf(float f) {
    __hip_bfloat16 h = __float2bfloat16(f);
    return __builtin_bit_cast(unsigned short, h);
}

__device__ __forceinline__ void gld_lds16(const void* g, void* s) {
    __builtin_amdgcn_global_load_lds(
        (__attribute__((address_space(1))) void*)(void*)g,
        (__attribute__((address_space(3))) void*)s, 16, 0, 0);
}

// ---------------------------------------------------------------------------
// fp32 -> bf16 cast (vectorized)
// ---------------------------------------------------------------------------
__global__ void cast_f32_to_bf16(const float* __restrict__ in,
                                 unsigned short* __restrict__ out, int n4) {
    int i = blockIdx.x * blockDim.x + threadIdx.x;
    if (i < n4) {
        float4 v = ((const float4*)in)[i];
        ushort4 u;
        u.x = f2bf(v.x); u.y = f2bf(v.y); u.z = f2bf(v.z); u.w = f2bf(v.w);
        ((ushort4*)out)[i] = u;
    }
}

// ---------------------------------------------------------------------------
// GEMM: C[m,n] = sum_k A[m,k] * B[n,k]   (A:[M,K] bf16, B:[N,K] bf16)
// m97 structure: 128x128 tile, BK=32, 4 waves (2x2), 16x16x32 MFMA,
// global_load_lds width-16 staging, linear LDS.
// ---------------------------------------------------------------------------
template<bool STORE_F32>
__global__ __launch_bounds__(256, 2)
void gemm_bt(const unsigned short* __restrict__ A,
             const unsigned short* __restrict__ B,
             void* __restrict__ C, int M, int N, int K) {
    (void)M;
    __shared__ unsigned short As[128 * 32];
    __shared__ unsigned short Bs[128 * 32];
    const int tid = threadIdx.x;
    const int nb = N >> 7;
    const int bm = blockIdx.x / nb;
    const int bn = blockIdx.x % nb;
    const int w  = tid >> 6, l = tid & 63;
    const int wr = w >> 1,  wc = w & 1;
    const int lr = l & 15,  lg = l >> 4;

    f32x4 acc[4][4] = {};

    const unsigned short* Ab = A + (size_t)bm * 128 * K;
    const unsigned short* Bb = B + (size_t)bn * 128 * K;

    const int c0 = tid, c1 = tid + 256;
    const int ar0 = c0 >> 2, ak0 = (c0 & 3) * 8;
    const int ar1 = c1 >> 2, ak1 = (c1 & 3) * 8;

    for (int kt = 0; kt < K; kt += 32) {
        __syncthreads();
        gld_lds16(Ab + (size_t)ar0 * K + kt + ak0, As + c0 * 8);
        gld_lds16(Ab + (size_t)ar1 * K + kt + ak1, As + c1 * 8);
        gld_lds16(Bb + (size_t)ar0 * K + kt + ak0, Bs + c0 * 8);
        gld_lds16(Bb + (size_t)ar1 * K + kt + ak1, Bs + c1 * 8);
        __syncthreads();

        bf16x8 af[4], bfr[4];
#pragma unroll
        for (int i = 0; i < 4; i++)
            af[i] = *(const bf16x8*)(As + (wr * 64 + i * 16 + lr) * 32 + lg * 8);
#pragma unroll
        for (int i = 0; i < 4; i++)
            bfr[i] = *(const bf16x8*)(Bs + (wc * 64 + i * 16 + lr) * 32 + lg * 8);
#pragma unroll
        for (int mi = 0; mi < 4; mi++)
#pragma unroll
            for (int ni = 0; ni < 4; ni++)
                acc[mi][ni] = __builtin_amdgcn_mfma_f32_16x16x32_bf16(
                    af[mi], bfr[ni], acc[mi][ni], 0, 0, 0);
    }

    const int row0 = bm * 128 + wr * 64;
    const int col0 = bn * 128 + wc * 64;
#pragma unroll
    for (int mi = 0; mi < 4; mi++)
#pragma unroll
        for (int ni = 0; ni < 4; ni++)
#pragma unroll
            for (int r = 0; r < 4; r++) {
                const int row = row0 + mi * 16 + lg * 4 + r;
                const int col = col0 + ni * 16 + lr;
                if (STORE_F32)
                    ((float*)C)[(size_t)row * N + col] = acc[mi][ni][r];
                else
                    ((unsigned short*)C)[(size_t)row * N + col] = f2bf(acc[mi][ni][r]);
            }
}

// ---------------------------------------------------------------------------
// Attention: qkv [4096][3072] bf16 (q|k|v, each head-contig 64), out [4096][1024] bf16
// Per block: one (b,h,q-tile of 64). 4 waves, each owns 16 q rows.
// Mask semantics: logit = (k<=q) ? dot/8 : 0; softmax over ALL 2048 k.
// ---------------------------------------------------------------------------
__global__ __launch_bounds__(256, 2)
void attn_kernel(const unsigned short* __restrict__ qkv,
                 unsigned short* __restrict__ out) {
    __shared__ unsigned short VT[64 * 72];      // V^T tile, padded stride 72
    __shared__ unsigned short Pl[4][16 * 72];   // per-wave P tile

    const int tid = threadIdx.x;
    const int w = tid >> 6, l = tid & 63, lr = l & 15, lg = l >> 4;
    const int bid = blockIdx.x;
    const int qt = bid & 31;
    const int h  = (bid >> 5) & 15;
    const int b  = bid >> 9;

    const size_t rowbase = (size_t)b * TSEQ;

    // Q fragments (A-operand): row = lr, k = lg*8.. ; two 32-wide k-steps
    const unsigned short* qp =
        qkv + (rowbase + qt * 64 + w * 16 + lr) * 3072 + h * 64 + lg * 8;
    const bf16x8 qf0 = *(const bf16x8*)qp;
    const bf16x8 qf1 = *(const bf16x8*)(qp + 32);

    f32x4 o[4] = {};
    float mrun[4] = {-3e38f, -3e38f, -3e38f, -3e38f};
    float lrun[4] = {0.f, 0.f, 0.f, 0.f};
    const int qrow = qt * 64 + w * 16 + lg * 4;  // + r

    const int vr = tid & 63, vcg = tid >> 6;

    for (int kt = 0; kt < TSEQ; kt += 64) {
        __syncthreads();
        // stage V^T: V[kt+r][d] -> VT[d][r]
        {
            const unsigned short* vp =
                qkv + (rowbase + kt + vr) * 3072 + 2048 + h * 64 + vcg * 16;
            u16x8 v0 = *(const u16x8*)vp;
            u16x8 v1 = *(const u16x8*)(vp + 8);
#pragma unroll
            for (int i = 0; i < 8; i++) VT[(vcg * 16 + i) * 72 + vr] = v0[i];
#pragma unroll
            for (int i = 0; i < 8; i++) VT[(vcg * 16 + 8 + i) * 72 + vr] = v1[i];
        }
        __syncthreads();

        // S = Q K^T / 8, masked
        float pv[4][4];
        float pmax[4] = {-3e38f, -3e38f, -3e38f, -3e38f};
#pragma unroll
        for (int f = 0; f < 4; f++) {
            const unsigned short* kp =
                qkv + (rowbase + kt + f * 16 + lr) * 3072 + 1024 + h * 64 + lg * 8;
            bf16x8 kb0 = *(const bf16x8*)kp;
            bf16x8 kb1 = *(const bf16x8*)(kp + 32);
            f32x4 z = {0.f, 0.f, 0.f, 0.f};
            f32x4 s = __builtin_amdgcn_mfma_f32_16x16x32_bf16(qf0, kb0, z, 0, 0, 0);
            s = __builtin_amdgcn_mfma_f32_16x16x32_bf16(qf1, kb1, s, 0, 0, 0);
            const int kcol = kt + f * 16 + lr;
#pragma unroll
            for (int r = 0; r < 4; r++) {
                float sv = s[r] * 0.125f;
                if (kcol > qrow + r) sv = 0.f;   // tril zeroing (NOT -inf)
                pv[f][r] = sv;
                pmax[r] = fmaxf(pmax[r], sv);
            }
        }
        // per-row max over 16 k-cols (lanes within lg-group)
#pragma unroll
        for (int d = 1; d < 16; d <<= 1)
#pragma unroll
            for (int r = 0; r < 4; r++)
                pmax[r] = fmaxf(pmax[r], __shfl_xor(pmax[r], d));
        float scl[4];
#pragma unroll
        for (int r = 0; r < 4; r++) {
            float mn = fmaxf(mrun[r], pmax[r]);
            scl[r] = __expf(mrun[r] - mn);
            mrun[r] = mn;
        }
        float rs[4] = {0.f, 0.f, 0.f, 0.f};
#pragma unroll
        for (int f = 0; f < 4; f++)
#pragma unroll
            for (int r = 0; r < 4; r++) {
                pv[f][r] = __expf(pv[f][r] - mrun[r]);
                rs[r] += pv[f][r];
            }
#pragma unroll
        for (int d = 1; d < 16; d <<= 1)
#pragma unroll
            for (int r = 0; r < 4; r++)
                rs[r] += __shfl_xor(rs[r], d);
#pragma unroll
        for (int r = 0; r < 4; r++) lrun[r] = lrun[r] * scl[r] + rs[r];
#pragma unroll
        for (int f2 = 0; f2 < 4; f2++)
#pragma unroll
            for (int r = 0; r < 4; r++) o[f2][r] *= scl[r];

        // P (D-layout) -> LDS -> A-layout fragments
        unsigned short* pw = &Pl[w][0];
#pragma unroll
        for (int f = 0; f < 4; f++)
#pragma unroll
            for (int r = 0; r < 4; r++)
                pw[(lg * 4 + r) * 72 + f * 16 + lr] = f2bf(pv[f][r]);
        __syncthreads();

        bf16x8 pa0 = *(const bf16x8*)(pw + lr * 72 + lg * 8);
        bf16x8 pa1 = *(const bf16x8*)(pw + lr * 72 + 32 + lg * 8);
#pragma unroll
        for (int f2 = 0; f2 < 4; f2++) {
            bf16x8 vb0 = *(const bf16x8*)(VT + (f2 * 16 + lr) * 72 + lg * 8);
            bf16x8 vb1 = *(const bf16x8*)(VT + (f2 * 16 + lr) * 72 + 32 + lg * 8);
            o[f2] = __builtin_amdgcn_mfma_f32_16x16x32_bf16(pa0, vb0, o[f2], 0, 0, 0);
            o[f2] = __builtin_amdgcn_mfma_f32_16x16x32_bf16(pa1, vb1, o[f2], 0, 0, 0);
        }
    }

    // epilogue: O /= l, store bf16
#pragma unroll
    for (int r = 0; r < 4; r++) {
        const float inv = 1.f / lrun[r];
#pragma unroll
        for (int f2 = 0; f2 < 4; f2++)
            out[(rowbase + qrow + r) * 1024 + h * 64 + f2 * 16 + lr] =
                f2bf(o[f2][r] * inv);
    }
}

// ---------------------------------------------------------------------------
extern "C" void kernel_launch(void* const* d_in, const int* in_sizes, int n_in,
                              void* d_out, int out_size, void* d_ws, size_t ws_size,
                              hipStream_t stream) {
    const float* x     = (const float*)d_in[0];
    const float* w_in  = (const float*)d_in[1];
    const float* w_out = (const float*)d_in[2];

    unsigned short* ws  = (unsigned short*)d_ws;
    unsigned short* xb  = ws;                            // 4096*1024
    unsigned short* wib = xb  + (size_t)4096 * 1024;     // 3072*1024
    unsigned short* wob = wib + (size_t)3072 * 1024;     // 1024*1024
    unsigned short* qkv = wob + (size_t)1024 * 1024;     // 4096*3072
    unsigned short* ao  = qkv + (size_t)4096 * 3072;     // 4096*1024

    cast_f32_to_bf16<<<4096, 256, 0, stream>>>(x, xb, 4096 * 1024 / 4);
    cast_f32_to_bf16<<<3072, 256, 0, stream>>>(w_in, wib, 3072 * 1024 / 4);
    cast_f32_to_bf16<<<1024, 256, 0, stream>>>(w_out, wob, 1024 * 1024 / 4);

    gemm_bt<false><<<(4096 / 128) * (3072 / 128), 256, 0, stream>>>(
        xb, wib, qkv, 4096, 3072, 1024);
    attn_kernel<<<2 * 16 * (TSEQ / 64), 256, 0, stream>>>(qkv, ao);
    gemm_bt<true><<<(4096 / 128) * (1024 / 128), 256, 0, stream>>>(
        ao, wob, (float*)d_out, 4096, 1024, 1024);
}